// Round 2
// baseline (635.896 us; speedup 1.0000x reference)
//
#include <hip/hip_runtime.h>
#include <math.h>

#define D 2048
#define S_LEN 4096
#define NB 4
#define NTOK (NB * S_LEN)  // 16384

__device__ __forceinline__ float gelu_tanh(float v) {
    const float c = 0.7978845608028654f;
    float t = tanhf(c * (v + 0.044715f * v * v * v));
    return 0.5f * v * (1.0f + t);
}

// ---------------- K1: u[t][r] = rsqrt(mean(x^2)+eps) * sum_d x[d]*nw[d]*V[d][r]
// one wave handles 4 tokens (V rows shared in regs across the 4 tokens)
__global__ __launch_bounds__(256) void k1_u_kernel(
        const float* __restrict__ x, const float* __restrict__ nw,
        const float* __restrict__ V, float* __restrict__ u)
{
    const int gwave = (blockIdx.x * 256 + threadIdx.x) >> 6;
    const int lane  = threadIdx.x & 63;
    const int t0 = gwave * 4;
    const float4* V4 = reinterpret_cast<const float4*>(V);

    float ss[4] = {0.f, 0.f, 0.f, 0.f};
    float uv[4][4] = {};

    #pragma unroll
    for (int j = 0; j < 8; ++j) {
        const int d0 = j * 256 + lane * 4;
        const float4 nw4 = *reinterpret_cast<const float4*>(nw + d0);
        float4 vr[4];
        #pragma unroll
        for (int i = 0; i < 4; ++i) vr[i] = V4[d0 + i];
        #pragma unroll
        for (int tk = 0; tk < 4; ++tk) {
            const float4 xv = *reinterpret_cast<const float4*>(x + (size_t)(t0 + tk) * D + d0);
            ss[tk] += xv.x*xv.x + xv.y*xv.y + xv.z*xv.z + xv.w*xv.w;
            const float z0 = xv.x*nw4.x, z1 = xv.y*nw4.y, z2 = xv.z*nw4.z, z3 = xv.w*nw4.w;
            uv[tk][0] += z0*vr[0].x + z1*vr[1].x + z2*vr[2].x + z3*vr[3].x;
            uv[tk][1] += z0*vr[0].y + z1*vr[1].y + z2*vr[2].y + z3*vr[3].y;
            uv[tk][2] += z0*vr[0].z + z1*vr[1].z + z2*vr[2].z + z3*vr[3].z;
            uv[tk][3] += z0*vr[0].w + z1*vr[1].w + z2*vr[2].w + z3*vr[3].w;
        }
    }
    #pragma unroll
    for (int m = 1; m < 64; m <<= 1) {
        #pragma unroll
        for (int tk = 0; tk < 4; ++tk) {
            ss[tk] += __shfl_xor(ss[tk], m);
            #pragma unroll
            for (int r = 0; r < 4; ++r) uv[tk][r] += __shfl_xor(uv[tk][r], m);
        }
    }
    if (lane < 16) {
        float ssv = ss[0], uvv = uv[0][0];
        #pragma unroll
        for (int tk = 0; tk < 4; ++tk)
            #pragma unroll
            for (int r = 0; r < 4; ++r)
                if (lane == tk * 4 + r) { ssv = ss[tk]; uvv = uv[tk][r]; }
        const float rstd = rsqrtf(ssv * (1.0f / 2048.0f) + 1e-6f);
        u[(size_t)t0 * 4 + lane] = rstd * uvv;  // contiguous 64B store
    }
}

// ---------------- K2: chunked scan over float4 (all 4 ranks at once), 1 block per batch
__global__ __launch_bounds__(256) void k2_scan_kernel(
        const float* __restrict__ u, const float* __restrict__ a_logit,
        float* __restrict__ hs)
{
    __shared__ float lds[256][5];  // stride 5: conflict-free
    const int b = blockIdx.x;
    const int i = threadIdx.x;
    float a[4];
    #pragma unroll
    for (int r = 0; r < 4; ++r) a[r] = 1.0f / (1.0f + expf(-a_logit[r]));

    const float4* up = reinterpret_cast<const float4*>(u)  + (size_t)b * S_LEN;
    float4*       hp = reinterpret_cast<float4*>(hs) + (size_t)b * S_LEN;

    float4 ul[16];
    float h[4] = {0.f, 0.f, 0.f, 0.f};
    const int s0 = i * 16;
    #pragma unroll
    for (int k = 0; k < 16; ++k) {
        ul[k] = up[s0 + k];
        h[0] = a[0]*h[0] + ul[k].x; h[1] = a[1]*h[1] + ul[k].y;
        h[2] = a[2]*h[2] + ul[k].z; h[3] = a[3]*h[3] + ul[k].w;
    }
    float m[4], run[4];
    #pragma unroll
    for (int r = 0; r < 4; ++r) {
        float a2 = a[r]*a[r], a4 = a2*a2, a8 = a4*a4;
        m[r] = a8*a8;  // a^16
        run[r] = h[r];
        lds[i][r] = run[r];
    }
    for (int off = 1; off < 256; off <<= 1) {
        __syncthreads();
        float v[4];
        #pragma unroll
        for (int r = 0; r < 4; ++r) v[r] = (i >= off) ? lds[i - off][r] : 0.f;
        __syncthreads();
        #pragma unroll
        for (int r = 0; r < 4; ++r) { run[r] += m[r]*v[r]; lds[i][r] = run[r]; m[r] *= m[r]; }
    }
    __syncthreads();
    float hh[4];
    #pragma unroll
    for (int r = 0; r < 4; ++r) hh[r] = (i == 0) ? 0.f : lds[i - 1][r];
    #pragma unroll
    for (int k = 0; k < 16; ++k) {
        hh[0] = a[0]*hh[0] + ul[k].x; hh[1] = a[1]*hh[1] + ul[k].y;
        hh[2] = a[2]*hh[2] + ul[k].z; hh[3] = a[3]*hh[3] + ul[k].w;
        hp[s0 + k] = make_float4(hh[0], hh[1], hh[2], hh[3]);
    }
}

// ---------------- K3: fused  x2 = x + hs*U^T ; rms2 ; t = gelu(n2@W1) ; out = x2 + t@W2
// ONE token per wave: x2 row cached in registers (8 float4/lane) across phases;
// no LDS, no barriers, no x re-read in phase C.
__global__ __launch_bounds__(256) void k3_fused_kernel(
        const float* __restrict__ x, const float* __restrict__ nw,
        const float* __restrict__ U, const float* __restrict__ hs,
        const float* __restrict__ W1, const float* __restrict__ W2,
        float* __restrict__ out)
{
    const int lane = threadIdx.x & 63;
    const int t = (blockIdx.x * 256 + threadIdx.x) >> 6;

    const float4 hv = reinterpret_cast<const float4*>(hs)[t];
    const float4* U4  = reinterpret_cast<const float4*>(U);
    const float4* W14 = reinterpret_cast<const float4*>(W1);
    const float4* W24 = reinterpret_cast<const float4*>(W2);
    const float4* x4  = reinterpret_cast<const float4*>(x) + (size_t)t * (D / 4);
    const float4* nwp = reinterpret_cast<const float4*>(nw);
    float4* out4 = reinterpret_cast<float4*>(out) + (size_t)t * (D / 4);

    float4 x2c[8];      // this lane's slice of x2 (32 floats), kept across phases
    float ss = 0.f;
    float pf[16] = {};

    // phase A: x2 = x + U·h ; ss += x2^2 ; pf[f] += (x2*nw)·W1[:,f]
    #pragma unroll
    for (int j = 0; j < 8; ++j) {
        const int q0 = j * 64 + lane;     // float4 index within the row
        const int d0 = q0 * 4;
        const float4 xv = x4[q0];
        const float4 nwv = nwp[q0];
        const float xa[4]  = {xv.x, xv.y, xv.z, xv.w};
        const float nwa[4] = {nwv.x, nwv.y, nwv.z, nwv.w};
        float x2a[4], z[4];
        #pragma unroll
        for (int i = 0; i < 4; ++i) {
            const float4 ur = U4[d0 + i];
            const float y = hv.x*ur.x + hv.y*ur.y + hv.z*ur.z + hv.w*ur.w;
            const float v = xa[i] + y;
            x2a[i] = v;
            ss += v * v;
            z[i] = v * nwa[i];
        }
        x2c[j] = make_float4(x2a[0], x2a[1], x2a[2], x2a[3]);
        #pragma unroll
        for (int i = 0; i < 4; ++i) {
            const float4* w1row = W14 + (size_t)(d0 + i) * 4;
            #pragma unroll
            for (int c = 0; c < 4; ++c) {
                const float4 wv = w1row[c];
                pf[c*4+0] += z[i]*wv.x; pf[c*4+1] += z[i]*wv.y;
                pf[c*4+2] += z[i]*wv.z; pf[c*4+3] += z[i]*wv.w;
            }
        }
    }

    // in-wave butterfly: all lanes end with full sums
    #pragma unroll
    for (int m = 1; m < 64; m <<= 1) {
        ss += __shfl_xor(ss, m);
        #pragma unroll
        for (int f = 0; f < 16; ++f) pf[f] += __shfl_xor(pf[f], m);
    }

    // gelu: lane computes f = lane&15, broadcast (mux tree avoids dynamic reg indexing)
    const float rstd = rsqrtf(ss * (1.0f / 2048.0f) + 1e-6f);
    const int fi = lane & 15;
    float sel = pf[0];
    #pragma unroll
    for (int f = 1; f < 16; ++f) sel = (fi == f) ? pf[f] : sel;
    const float g = gelu_tanh(rstd * sel);
    float tv[16];
    #pragma unroll
    for (int f = 0; f < 16; ++f) tv[f] = __shfl(g, f);

    // phase C: out = x2 + t @ W2 (x2 from registers; W2 loads perfectly coalesced)
    #pragma unroll
    for (int j = 0; j < 8; ++j) {
        const int q0 = j * 64 + lane;
        float4 acc = x2c[j];
        #pragma unroll
        for (int f = 0; f < 16; ++f) {
            const float4 wv = W24[(size_t)f * (D / 4) + q0];
            acc.x += tv[f]*wv.x; acc.y += tv[f]*wv.y;
            acc.z += tv[f]*wv.z; acc.w += tv[f]*wv.w;
        }
        out4[q0] = acc;
    }
}

extern "C" void kernel_launch(void* const* d_in, const int* in_sizes, int n_in,
                              void* d_out, int out_size, void* d_ws, size_t ws_size,
                              hipStream_t stream)
{
    (void)in_sizes; (void)n_in; (void)out_size; (void)ws_size;
    const float* x  = (const float*)d_in[0];
    const float* nw = (const float*)d_in[1];
    const float* V  = (const float*)d_in[2];
    const float* U  = (const float*)d_in[3];
    const float* al = (const float*)d_in[4];
    const float* W1 = (const float*)d_in[5];
    const float* W2 = (const float*)d_in[6];
    float* out = (float*)d_out;
    float* u   = (float*)d_ws;                 // [NTOK][4]
    float* hs  = u + (size_t)NTOK * 4;         // [NTOK][4]

    k1_u_kernel   <<<dim3(NTOK / 16), dim3(256), 0, stream>>>(x, nw, V, u);
    k2_scan_kernel<<<dim3(NB),        dim3(256), 0, stream>>>(u, al, hs);
    k3_fused_kernel<<<dim3(NTOK / 4), dim3(256), 0, stream>>>(x, nw, U, hs, W1, W2, out);
}

// Round 3
// 629.806 us; speedup vs baseline: 1.0097x; 1.0097x over previous
//
#include <hip/hip_runtime.h>
#include <math.h>

#define D 2048
#define DQ (D / 4)          // 512 float4 per row
#define S_LEN 4096
#define NB 4
#define NTOK (NB * S_LEN)   // 16384

__device__ __forceinline__ float gelu_tanh(float v) {
    const float c = 0.7978845608028654f;
    float t = tanhf(c * (v + 0.044715f * v * v * v));
    return 0.5f * v * (1.0f + t);
}

// ---------------- KT: transpose V,U,W1 into [r][D] / [f][D] layouts (ws scratch)
__global__ __launch_bounds__(256) void kt_transpose(
        const float* __restrict__ V, const float* __restrict__ U,
        const float* __restrict__ W1,
        float* __restrict__ VT, float* __restrict__ UT, float* __restrict__ W1T)
{
    const int i = blockIdx.x * 256 + threadIdx.x;  // dim index 0..2047
    #pragma unroll
    for (int r = 0; r < 4; ++r) {
        VT[r * D + i] = V[i * 4 + r];
        UT[r * D + i] = U[i * 4 + r];
    }
    #pragma unroll
    for (int f = 0; f < 16; ++f) W1T[f * D + i] = W1[i * 16 + f];
}

// ---------------- K1: u[t][r] = rstd(x) * sum_d x[d]*nw[d]*VT[r][d]
// 4 tokens per wave; ALL loads coalesced 64-lane float4
__global__ __launch_bounds__(256) void k1_u_kernel(
        const float* __restrict__ x, const float* __restrict__ nw,
        const float* __restrict__ VT, float* __restrict__ u)
{
    const int gwave = (blockIdx.x * 256 + threadIdx.x) >> 6;
    const int lane  = threadIdx.x & 63;
    const int t0 = gwave * 4;
    const float4* VT4 = reinterpret_cast<const float4*>(VT);
    const float4* x4  = reinterpret_cast<const float4*>(x);
    const float4* nwp = reinterpret_cast<const float4*>(nw);

    float ss[4] = {0.f, 0.f, 0.f, 0.f};
    float uv[4][4] = {};

    #pragma unroll
    for (int j = 0; j < 8; ++j) {
        const int q0 = j * 64 + lane;
        const float4 nwv = nwp[q0];
        float4 vt[4];
        #pragma unroll
        for (int r = 0; r < 4; ++r) vt[r] = VT4[r * DQ + q0];
        #pragma unroll
        for (int tk = 0; tk < 4; ++tk) {
            const float4 xv = x4[(size_t)(t0 + tk) * DQ + q0];
            ss[tk] += xv.x*xv.x + xv.y*xv.y + xv.z*xv.z + xv.w*xv.w;
            const float z0 = xv.x*nwv.x, z1 = xv.y*nwv.y, z2 = xv.z*nwv.z, z3 = xv.w*nwv.w;
            #pragma unroll
            for (int r = 0; r < 4; ++r)
                uv[tk][r] += z0*vt[r].x + z1*vt[r].y + z2*vt[r].z + z3*vt[r].w;
        }
    }
    #pragma unroll
    for (int m = 1; m < 64; m <<= 1) {
        #pragma unroll
        for (int tk = 0; tk < 4; ++tk) {
            ss[tk] += __shfl_xor(ss[tk], m);
            #pragma unroll
            for (int r = 0; r < 4; ++r) uv[tk][r] += __shfl_xor(uv[tk][r], m);
        }
    }
    if (lane < 16) {
        float ssv = ss[0], uvv = uv[0][0];
        #pragma unroll
        for (int tk = 0; tk < 4; ++tk)
            #pragma unroll
            for (int r = 0; r < 4; ++r)
                if (lane == tk * 4 + r) { ssv = ss[tk]; uvv = uv[tk][r]; }
        const float rstd = rsqrtf(ssv * (1.0f / 2048.0f) + 1e-6f);
        u[(size_t)t0 * 4 + lane] = rstd * uvv;
    }
}

// ---------------- K2: chunked scan, IN-PLACE (uh read then overwritten), 1 block/batch
__global__ __launch_bounds__(256) void k2_scan_kernel(
        float* uh, const float* __restrict__ a_logit)
{
    __shared__ float lds[256][5];
    const int b = blockIdx.x;
    const int i = threadIdx.x;
    float a[4];
    #pragma unroll
    for (int r = 0; r < 4; ++r) a[r] = 1.0f / (1.0f + expf(-a_logit[r]));

    float4* up = reinterpret_cast<float4*>(uh) + (size_t)b * S_LEN;

    float4 ul[16];
    float h[4] = {0.f, 0.f, 0.f, 0.f};
    const int s0 = i * 16;
    #pragma unroll
    for (int k = 0; k < 16; ++k) {
        ul[k] = up[s0 + k];
        h[0] = a[0]*h[0] + ul[k].x; h[1] = a[1]*h[1] + ul[k].y;
        h[2] = a[2]*h[2] + ul[k].z; h[3] = a[3]*h[3] + ul[k].w;
    }
    float m[4], run[4];
    #pragma unroll
    for (int r = 0; r < 4; ++r) {
        float a2 = a[r]*a[r], a4 = a2*a2, a8 = a4*a4;
        m[r] = a8*a8;  // a^16
        run[r] = h[r];
        lds[i][r] = run[r];
    }
    for (int off = 1; off < 256; off <<= 1) {
        __syncthreads();
        float v[4];
        #pragma unroll
        for (int r = 0; r < 4; ++r) v[r] = (i >= off) ? lds[i - off][r] : 0.f;
        __syncthreads();
        #pragma unroll
        for (int r = 0; r < 4; ++r) { run[r] += m[r]*v[r]; lds[i][r] = run[r]; m[r] *= m[r]; }
    }
    __syncthreads();
    float hh[4];
    #pragma unroll
    for (int r = 0; r < 4; ++r) hh[r] = (i == 0) ? 0.f : lds[i - 1][r];
    #pragma unroll
    for (int k = 0; k < 16; ++k) {
        hh[0] = a[0]*hh[0] + ul[k].x; hh[1] = a[1]*hh[1] + ul[k].y;
        hh[2] = a[2]*hh[2] + ul[k].z; hh[3] = a[3]*hh[3] + ul[k].w;
        up[s0 + k] = make_float4(hh[0], hh[1], hh[2], hh[3]);
    }
}

// ---------------- K3: fused  x2 = x + hs*U^T ; rms2 ; t = gelu(n2@W1) ; out = x2 + t@W2
// 4 tokens per wave (weights amortized), all loads coalesced via UT/W1T.
__global__ __launch_bounds__(256) void k3_fused_kernel(
        const float* __restrict__ x, const float* __restrict__ nw,
        const float* __restrict__ UT, const float* __restrict__ hs,
        const float* __restrict__ W1T, const float* __restrict__ W2,
        float* __restrict__ out)
{
    const int lane = threadIdx.x & 63;
    const int gwave = (blockIdx.x * 256 + threadIdx.x) >> 6;
    const int t0 = gwave * 4;

    const float4* UT4  = reinterpret_cast<const float4*>(UT);
    const float4* W1T4 = reinterpret_cast<const float4*>(W1T);
    const float4* W24  = reinterpret_cast<const float4*>(W2);
    const float4* x4   = reinterpret_cast<const float4*>(x);
    const float4* nwp  = reinterpret_cast<const float4*>(nw);
    float4* out4 = reinterpret_cast<float4*>(out);

    float4 hv[4];
    #pragma unroll
    for (int tk = 0; tk < 4; ++tk) hv[tk] = reinterpret_cast<const float4*>(hs)[t0 + tk];

    float ss[4] = {0.f, 0.f, 0.f, 0.f};
    float pf[4][16] = {};

    // phase A: x2 = x + UT^T h ; ss += x2^2 ; pf[tk][f] += (x2*nw)·W1T[f]
    #pragma unroll
    for (int j = 0; j < 8; ++j) {
        const int q0 = j * 64 + lane;
        const float4 nwv = nwp[q0];
        float4 ut[4];
        #pragma unroll
        for (int r = 0; r < 4; ++r) ut[r] = UT4[r * DQ + q0];
        float4 z4[4];
        #pragma unroll
        for (int tk = 0; tk < 4; ++tk) {
            const float4 xv = x4[(size_t)(t0 + tk) * DQ + q0];
            float4 x2;
            x2.x = xv.x + hv[tk].x*ut[0].x + hv[tk].y*ut[1].x + hv[tk].z*ut[2].x + hv[tk].w*ut[3].x;
            x2.y = xv.y + hv[tk].x*ut[0].y + hv[tk].y*ut[1].y + hv[tk].z*ut[2].y + hv[tk].w*ut[3].y;
            x2.z = xv.z + hv[tk].x*ut[0].z + hv[tk].y*ut[1].z + hv[tk].z*ut[2].z + hv[tk].w*ut[3].z;
            x2.w = xv.w + hv[tk].x*ut[0].w + hv[tk].y*ut[1].w + hv[tk].z*ut[2].w + hv[tk].w*ut[3].w;
            ss[tk] += x2.x*x2.x + x2.y*x2.y + x2.z*x2.z + x2.w*x2.w;
            z4[tk] = make_float4(x2.x*nwv.x, x2.y*nwv.y, x2.z*nwv.z, x2.w*nwv.w);
        }
        #pragma unroll
        for (int f = 0; f < 16; ++f) {
            const float4 wv = W1T4[f * DQ + q0];
            #pragma unroll
            for (int tk = 0; tk < 4; ++tk)
                pf[tk][f] += z4[tk].x*wv.x + z4[tk].y*wv.y + z4[tk].z*wv.z + z4[tk].w*wv.w;
        }
    }

    // butterfly: all lanes end with full sums (68 values)
    #pragma unroll
    for (int m = 1; m < 64; m <<= 1) {
        #pragma unroll
        for (int tk = 0; tk < 4; ++tk) {
            ss[tk] += __shfl_xor(ss[tk], m);
            #pragma unroll
            for (int f = 0; f < 16; ++f) pf[tk][f] += __shfl_xor(pf[tk][f], m);
        }
    }

    // gelu: lane handles (tk = lane>>4, f = lane&15), then broadcast
    const int mytk = lane >> 4;
    float ssv = ss[0];
    #pragma unroll
    for (int tk = 1; tk < 4; ++tk) ssv = (mytk == tk) ? ss[tk] : ssv;
    float sel = pf[0][0];
    #pragma unroll
    for (int tk = 0; tk < 4; ++tk)
        #pragma unroll
        for (int f = 0; f < 16; ++f)
            if (tk || f) sel = (lane == tk * 16 + f) ? pf[tk][f] : sel;
    const float rstd = rsqrtf(ssv * (1.0f / 2048.0f) + 1e-6f);
    const float g = gelu_tanh(rstd * sel);
    float tv[4][16];
    #pragma unroll
    for (int tk = 0; tk < 4; ++tk)
        #pragma unroll
        for (int f = 0; f < 16; ++f) tv[tk][f] = __shfl(g, tk * 16 + f);

    // phase C: out = x2 + t @ W2  (x2 recomputed; x row L3-hot)
    #pragma unroll
    for (int j = 0; j < 8; ++j) {
        const int q0 = j * 64 + lane;
        float4 ut[4];
        #pragma unroll
        for (int r = 0; r < 4; ++r) ut[r] = UT4[r * DQ + q0];
        float4 acc[4];
        #pragma unroll
        for (int tk = 0; tk < 4; ++tk) {
            const float4 xv = x4[(size_t)(t0 + tk) * DQ + q0];
            acc[tk].x = xv.x + hv[tk].x*ut[0].x + hv[tk].y*ut[1].x + hv[tk].z*ut[2].x + hv[tk].w*ut[3].x;
            acc[tk].y = xv.y + hv[tk].x*ut[0].y + hv[tk].y*ut[1].y + hv[tk].z*ut[2].y + hv[tk].w*ut[3].y;
            acc[tk].z = xv.z + hv[tk].x*ut[0].z + hv[tk].y*ut[1].z + hv[tk].z*ut[2].z + hv[tk].w*ut[3].z;
            acc[tk].w = xv.w + hv[tk].x*ut[0].w + hv[tk].y*ut[1].w + hv[tk].z*ut[2].w + hv[tk].w*ut[3].w;
        }
        #pragma unroll
        for (int f = 0; f < 16; ++f) {
            const float4 wv = W24[(size_t)f * DQ + q0];
            #pragma unroll
            for (int tk = 0; tk < 4; ++tk) {
                acc[tk].x += tv[tk][f]*wv.x; acc[tk].y += tv[tk][f]*wv.y;
                acc[tk].z += tv[tk][f]*wv.z; acc[tk].w += tv[tk][f]*wv.w;
            }
        }
        #pragma unroll
        for (int tk = 0; tk < 4; ++tk)
            out4[(size_t)(t0 + tk) * DQ + q0] = acc[tk];
    }
}

extern "C" void kernel_launch(void* const* d_in, const int* in_sizes, int n_in,
                              void* d_out, int out_size, void* d_ws, size_t ws_size,
                              hipStream_t stream)
{
    (void)in_sizes; (void)n_in; (void)out_size; (void)ws_size;
    const float* x  = (const float*)d_in[0];
    const float* nw = (const float*)d_in[1];
    const float* V  = (const float*)d_in[2];
    const float* U  = (const float*)d_in[3];
    const float* al = (const float*)d_in[4];
    const float* W1 = (const float*)d_in[5];
    const float* W2 = (const float*)d_in[6];
    float* out = (float*)d_out;

    float* u   = (float*)d_ws;                    // [NTOK][4] = 256 KB, becomes hs in-place
    float* VT  = u  + (size_t)NTOK * 4;           // [4][D]  = 32 KB
    float* UT  = VT + (size_t)4 * D;              // [4][D]  = 32 KB
    float* W1T = UT + (size_t)4 * D;              // [16][D] = 128 KB   (total 448 KB)

    kt_transpose  <<<dim3(D / 256),  dim3(256), 0, stream>>>(V, U, W1, VT, UT, W1T);
    k1_u_kernel   <<<dim3(NTOK / 16), dim3(256), 0, stream>>>(x, nw, VT, u);
    k2_scan_kernel<<<dim3(NB),        dim3(256), 0, stream>>>(u, al);
    k3_fused_kernel<<<dim3(NTOK / 16), dim3(256), 0, stream>>>(x, nw, UT, u, W1T, W2, out);
}